// Round 3
// baseline (326.724 us; speedup 1.0000x reference)
//
#include <hip/hip_runtime.h>
#include <hip/hip_cooperative_groups.h>

namespace cg = cooperative_groups;

// Bahdanau multi-head attention, fp32, B=2 L=128 D=512 H=8 dh=64.
// R2: ONE cooperative kernel (256 blocks x 512 thr, 1 block/CU), 3 grid syncs.
//     GEMM phases = direct cache-fed dot products (no LDS, no barriers).
//     Attn phase: QPB=8, per-thread (k, f-quarter) partials, Lv pruning.

#define NHEADS 8
#define DH 64
#define DM 512
#define BB 2
#define LQL 128
#define LKL 128
#define QPB 8

static __device__ __forceinline__ float fexp2(float x) { return __builtin_amdgcn_exp2f(x); }
static __device__ __forceinline__ float frcp(float x)  { return __builtin_amdgcn_rcpf(x); }

struct P {
    const float *xq, *xk, *xv, *Wq, *Wk, *Wv, *Wo, *Wqa, *Wka, *wv;
    const int* vl;
    float *Q, *K, *V, *qf, *kf, *inter, *out;
};

static __device__ __forceinline__ float dot512(const float* __restrict__ a,
                                               const float* __restrict__ b) {
    const float4* A = (const float4*)a;
    const float4* B = (const float4*)b;
    float s0 = 0.f, s1 = 0.f, s2 = 0.f, s3 = 0.f;
    #pragma unroll 4
    for (int i = 0; i < 128; i += 4) {
        float4 a0 = A[i+0], b0 = B[i+0];
        float4 a1 = A[i+1], b1 = B[i+1];
        float4 a2 = A[i+2], b2 = B[i+2];
        float4 a3 = A[i+3], b3 = B[i+3];
        s0 = fmaf(a0.x,b0.x, fmaf(a0.y,b0.y, fmaf(a0.z,b0.z, fmaf(a0.w,b0.w, s0))));
        s1 = fmaf(a1.x,b1.x, fmaf(a1.y,b1.y, fmaf(a1.z,b1.z, fmaf(a1.w,b1.w, s1))));
        s2 = fmaf(a2.x,b2.x, fmaf(a2.y,b2.y, fmaf(a2.z,b2.z, fmaf(a2.w,b2.w, s2))));
        s3 = fmaf(a3.x,b3.x, fmaf(a3.y,b3.y, fmaf(a3.z,b3.z, fmaf(a3.w,b3.w, s3))));
    }
    return (s0 + s1) + (s2 + s3);
}

static __device__ __forceinline__ float dot64(const float* __restrict__ a,
                                              const float* __restrict__ b) {
    const float4* A = (const float4*)a;
    const float4* B = (const float4*)b;
    float s0 = 0.f, s1 = 0.f, s2 = 0.f, s3 = 0.f;
    #pragma unroll
    for (int i = 0; i < 16; i += 4) {
        float4 a0 = A[i+0], b0 = B[i+0];
        float4 a1 = A[i+1], b1 = B[i+1];
        float4 a2 = A[i+2], b2 = B[i+2];
        float4 a3 = A[i+3], b3 = B[i+3];
        s0 = fmaf(a0.x,b0.x, fmaf(a0.y,b0.y, fmaf(a0.z,b0.z, fmaf(a0.w,b0.w, s0))));
        s1 = fmaf(a1.x,b1.x, fmaf(a1.y,b1.y, fmaf(a1.z,b1.z, fmaf(a1.w,b1.w, s1))));
        s2 = fmaf(a2.x,b2.x, fmaf(a2.y,b2.y, fmaf(a2.z,b2.z, fmaf(a2.w,b2.w, s2))));
        s3 = fmaf(a3.x,b3.x, fmaf(a3.y,b3.y, fmaf(a3.z,b3.z, fmaf(a3.w,b3.w, s3))));
    }
    return (s0 + s1) + (s2 + s3);
}

// Phase A: Q/K/V projections. 768 jobs of 32 rows x 16 cols, K=512.
static __device__ void phaseA(const P& p, int bid, int t) {
    for (int job = bid; job < 768; job += 256) {
        const int mat = job >> 8;
        const int jj  = job & 255;
        const int r = ((jj >> 5) << 5) + (t >> 4);
        const int c = ((jj & 31) << 4) + (t & 15);
        const float* A; const float* W; float* C;
        if (mat == 0)      { A = p.xq; W = p.Wq; C = p.Q; }
        else if (mat == 1) { A = p.xk; W = p.Wk; C = p.K; }
        else               { A = p.xv; W = p.Wv; C = p.V; }
        if (mat != 0) {                         // K,V rows >= valid_len never used
            const int b = r >> 7, l = r & 127;
            if (l >= p.vl[b]) continue;
        }
        C[(size_t)r * DM + c] = dot512(A + (size_t)r * DM, W + (size_t)c * DM);
    }
}

// Phase B: qf/kf features. 4096 jobs of 32 rows x 16 cols, K=64, gathered rows.
static __device__ void phaseB(const P& p, int bid, int t) {
    for (int job = bid; job < 4096; job += 256) {
        const int mat = job >> 11;
        const int jj  = job & 2047;
        const int r = ((jj >> 5) << 5) + (t >> 4);   // (b,h,l)-flattened, 0..2047
        const int c = ((jj & 31) << 4) + (t & 15);
        const int b = r >> 10, h = (r >> 7) & 7, l = r & 127;
        if (mat == 1 && l >= p.vl[b]) continue;      // masked kf rows never read
        const float* Arow = (mat ? p.K : p.Q) + (size_t)(b * LQL + l) * DM + h * DH;
        const float* Wrow = (mat ? p.Wka : p.Wqa) + (size_t)c * DH;
        float* C = mat ? p.kf : p.qf;
        C[(size_t)r * DM + c] = dot64(Arow, Wrow);
    }
}

// Phase C: fused score + masked softmax + PV. 256 jobs (b,h,qtile), 1/block.
static __device__ void phaseC(const P& p, int bid, int t) {
    __shared__ float s_qf2[QPB][DM];       // qf * 2log2e            (16 KB)
    __shared__ float s_wv2[DM];            // wv * -2                ( 2 KB)
    __shared__ float s_part[4][QPB][LKL];  // per-f-quarter partials (16 KB)
    __shared__ float s_attn[QPB][LKL];     //                        ( 4 KB)

    const float C2 = 2.8853900818f;        // 2*log2(e)
    const float LOG2E = 1.4426950409f;

    const int b  = bid >> 7;
    const int h  = (bid >> 4) & 7;
    const int qt = bid & 15;
    const int qbase = qt * QPB;
    const int bh = b * NHEADS + h;
    const int Lv = p.vl[b];

    {   // stage qf (pre-scaled) and wv (pre-scaled by -2)
        const int r = t >> 6, cc = (t & 63) * 8;
        const float4* q4 = (const float4*)(p.qf + ((size_t)(bh * LQL + qbase + r)) * DM + cc);
        float4 v0 = q4[0], v1 = q4[1];
        s_qf2[r][cc+0] = v0.x * C2; s_qf2[r][cc+1] = v0.y * C2;
        s_qf2[r][cc+2] = v0.z * C2; s_qf2[r][cc+3] = v0.w * C2;
        s_qf2[r][cc+4] = v1.x * C2; s_qf2[r][cc+5] = v1.y * C2;
        s_qf2[r][cc+6] = v1.z * C2; s_qf2[r][cc+7] = v1.w * C2;
        s_wv2[t] = p.wv[t] * -2.0f;
    }
    __syncthreads();

    const int k = t & 127, fq = t >> 7;
    float acc[QPB] = {};
    if (k < Lv) {                           // fully-masked waves skip 134M evals
        const float* kp = p.kf + ((size_t)(bh * LKL + k)) * DM + fq * 128;
        float4 kA = *(const float4*)kp;
        float4 kB = *(const float4*)(kp + 4);
        #pragma unroll 1
        for (int it = 0; it < 16; ++it) {
            float4 nA, nB;
            if (it < 15) { nA = *(const float4*)(kp + 8); nB = *(const float4*)(kp + 12); }
            else         { nA = kA; nB = kB; }
            const int f0 = fq * 128 + it * 8;
            const float4 w0 = *(const float4*)&s_wv2[f0];
            const float4 w1 = *(const float4*)&s_wv2[f0 + 4];
            #pragma unroll
            for (int q = 0; q < QPB; ++q) {
                const float4 q0 = *(const float4*)&s_qf2[q][f0];
                const float4 q1 = *(const float4*)&s_qf2[q][f0 + 4];
                float a = acc[q];
                a = fmaf(w0.x, frcp(fexp2(fmaf(kA.x, C2, q0.x)) + 1.f), a);
                a = fmaf(w0.y, frcp(fexp2(fmaf(kA.y, C2, q0.y)) + 1.f), a);
                a = fmaf(w0.z, frcp(fexp2(fmaf(kA.z, C2, q0.z)) + 1.f), a);
                a = fmaf(w0.w, frcp(fexp2(fmaf(kA.w, C2, q0.w)) + 1.f), a);
                a = fmaf(w1.x, frcp(fexp2(fmaf(kB.x, C2, q1.x)) + 1.f), a);
                a = fmaf(w1.y, frcp(fexp2(fmaf(kB.y, C2, q1.y)) + 1.f), a);
                a = fmaf(w1.z, frcp(fexp2(fmaf(kB.z, C2, q1.z)) + 1.f), a);
                a = fmaf(w1.w, frcp(fexp2(fmaf(kB.w, C2, q1.w)) + 1.f), a);
                acc[q] = a;
            }
            kA = nA; kB = nB; kp += 8;
        }
    }
    #pragma unroll
    for (int q = 0; q < QPB; ++q) s_part[fq][q][k] = acc[q];
    __syncthreads();

    {   // masked softmax: wave w = q-row w; lane covers k=lane, k=lane+64
        const int q = t >> 6, lane = t & 63;
        float v0 = -3.0e38f, v1 = -3.0e38f;
        if (lane < Lv)
            v0 = s_part[0][q][lane] + s_part[1][q][lane]
               + s_part[2][q][lane] + s_part[3][q][lane];
        if (lane + 64 < Lv)
            v1 = s_part[0][q][lane+64] + s_part[1][q][lane+64]
               + s_part[2][q][lane+64] + s_part[3][q][lane+64];
        float m = fmaxf(v0, v1);
        #pragma unroll
        for (int off = 32; off; off >>= 1) m = fmaxf(m, __shfl_xor(m, off, 64));
        const float e0 = fexp2((v0 - m) * LOG2E);   // masked lanes -> exactly 0
        const float e1 = fexp2((v1 - m) * LOG2E);
        float s = e0 + e1;
        #pragma unroll
        for (int off = 32; off; off >>= 1) s += __shfl_xor(s, off, 64);
        const float inv = frcp(s);
        s_attn[q][lane]      = e0 * inv;
        s_attn[q][lane + 64] = e1 * inv;
    }
    __syncthreads();

    {   // PV: thread (q = t>>6, d = t&63); only k < Lv contribute
        const int q = t >> 6, d = t & 63;
        const float* vb = p.V + ((size_t)(b * LKL)) * DM + h * DH + d;
        float a0 = 0.f, a1 = 0.f, a2 = 0.f, a3 = 0.f;
        int kk = 0;
        for (; kk + 4 <= Lv; kk += 4) {
            a0 += s_attn[q][kk+0] * vb[(size_t)(kk+0) * DM];
            a1 += s_attn[q][kk+1] * vb[(size_t)(kk+1) * DM];
            a2 += s_attn[q][kk+2] * vb[(size_t)(kk+2) * DM];
            a3 += s_attn[q][kk+3] * vb[(size_t)(kk+3) * DM];
        }
        for (; kk < Lv; ++kk) a0 += s_attn[q][kk] * vb[(size_t)kk * DM];
        p.inter[((size_t)(b * LQL + qbase + q)) * DM + h * DH + d] = (a0 + a1) + (a2 + a3);
    }
}

// Phase D: out = inter @ Wo^T. 256 jobs of 32 rows x 16 cols, K=512.
static __device__ void phaseD(const P& p, int bid, int t) {
    const int r = ((bid >> 5) << 5) + (t >> 4);
    const int c = ((bid & 31) << 4) + (t & 15);
    p.out[(size_t)r * DM + c] = dot512(p.inter + (size_t)r * DM, p.Wo + (size_t)c * DM);
}

__global__ __launch_bounds__(512, 1) void fused_coop_kernel(P p) {
    cg::grid_group g = cg::this_grid();
    const int bid = blockIdx.x, t = threadIdx.x;
    phaseA(p, bid, t);
    g.sync();
    phaseB(p, bid, t);
    g.sync();
    phaseC(p, bid, t);
    g.sync();
    phaseD(p, bid, t);
}

// Fallback path (identical math, 4 launches) if cooperative launch unsupported.
__global__ __launch_bounds__(512) void kA_kernel(P p) { phaseA(p, blockIdx.x, threadIdx.x); }
__global__ __launch_bounds__(512) void kB_kernel(P p) { phaseB(p, blockIdx.x, threadIdx.x); }
__global__ __launch_bounds__(512) void kC_kernel(P p) { phaseC(p, blockIdx.x, threadIdx.x); }
__global__ __launch_bounds__(512) void kD_kernel(P p) { phaseD(p, blockIdx.x, threadIdx.x); }

extern "C" void kernel_launch(void* const* d_in, const int* in_sizes, int n_in,
                              void* d_out, int out_size, void* d_ws, size_t ws_size,
                              hipStream_t stream)
{
    float* ws = (float*)d_ws;
    P p;
    p.xq  = (const float*)d_in[0];
    p.xk  = (const float*)d_in[1];
    p.xv  = (const float*)d_in[2];
    p.vl  = (const int*)d_in[3];
    p.Wq  = (const float*)d_in[4];
    p.Wk  = (const float*)d_in[5];
    p.Wv  = (const float*)d_in[6];
    p.Wo  = (const float*)d_in[7];
    p.Wqa = (const float*)d_in[8];
    p.Wka = (const float*)d_in[9];
    p.wv  = (const float*)d_in[10];
    // ws layout (floats): Q[131072] K[131072] V[131072] qf[1048576] kf[1048576] inter[131072]
    p.Q     = ws;
    p.K     = ws + 131072;
    p.V     = ws + 262144;
    p.qf    = ws + 393216;
    p.kf    = ws + 393216 + 1048576;
    p.inter = ws + 393216 + 2097152;
    p.out   = (float*)d_out;

    void* args[] = { &p };
    hipError_t e = hipLaunchCooperativeKernel((const void*)fused_coop_kernel,
                                              dim3(256), dim3(512), args, 0, stream);
    if (e != hipSuccess) {
        kA_kernel<<<dim3(256), dim3(512), 0, stream>>>(p);
        kB_kernel<<<dim3(256), dim3(512), 0, stream>>>(p);
        kC_kernel<<<dim3(256), dim3(512), 0, stream>>>(p);
        kD_kernel<<<dim3(256), dim3(512), 0, stream>>>(p);
    }
}

// Round 4
// 64.371 us; speedup vs baseline: 5.0756x; 5.0756x over previous
//
#include <hip/hip_runtime.h>

// Bahdanau multi-head attention, fp32 in/out, B=2 L=128 D=512 H=8 dh=64.
// R4: back to 4 separate launches (R2 structure, measured best) but the three
//     GEMM stages use fp16 MFMA (16x16x32_f16, fp32 accum). Attn core fp32.

#define NHEADS 8
#define DH 64
#define DM 512
#define BB 2
#define LQL 128
#define LKL 128
#define QPB 8

typedef _Float16 v8h __attribute__((ext_vector_type(8)));
typedef float v4f __attribute__((ext_vector_type(4)));

static __device__ __forceinline__ float fexp2(float x) { return __builtin_amdgcn_exp2f(x); }
static __device__ __forceinline__ float frcp(float x)  { return __builtin_amdgcn_rcpf(x); }

static __device__ __forceinline__ v8h cvt8(const float4 a, const float4 b) {
    v8h h;
    h[0] = (_Float16)a.x; h[1] = (_Float16)a.y; h[2] = (_Float16)a.z; h[3] = (_Float16)a.w;
    h[4] = (_Float16)b.x; h[5] = (_Float16)b.y; h[6] = (_Float16)b.z; h[7] = (_Float16)b.w;
    return h;
}

// ---------------- Stage 1: Q/K/V = X @ W^T via MFMA -------------------------
// 64x64 tile, 256 thr (4 waves), wave w = 16-row strip, 4 n-subtiles, K=512.
// Q,K stored fp16 (consumed by feat MFMA); V stored fp32 (consumed by PV).
__global__ __launch_bounds__(256) void qkv_mfma(
    const float* __restrict__ xq, const float* __restrict__ xk, const float* __restrict__ xv,
    const float* __restrict__ Wq, const float* __restrict__ Wk, const float* __restrict__ Wv,
    const int* __restrict__ vl,
    _Float16* __restrict__ Qh, _Float16* __restrict__ Kh, float* __restrict__ V)
{
    const int mat = blockIdx.z;
    const float* A; const float* W;
    if (mat == 0)      { A = xq; W = Wq; }
    else if (mat == 1) { A = xk; W = Wk; }
    else               { A = xv; W = Wv; }
    const int bm0 = blockIdx.y * 64, bn0 = blockIdx.x * 64;
    // K/V rows l >= valid_len are never read downstream -> whole-tile skip
    if (mat && (bm0 & 127) >= vl[bm0 >> 7]) return;

    __shared__ _Float16 As[64][40];   // stride 40 halves = 80B: b128-aligned, ~conflict-free
    __shared__ _Float16 Ws[64][40];
    const int tid = threadIdx.x, wave = tid >> 6, lane = tid & 63;
    const int srow = tid >> 2, sseg = tid & 3;
    const int fr = lane & 15, fg = (lane >> 4) * 8;

    v4f acc[4] = {};
    for (int k0 = 0; k0 < DM; k0 += 32) {
        const float4* ap = (const float4*)(A + (size_t)(bm0 + srow) * DM + k0 + sseg * 8);
        const float4 a0 = ap[0], a1 = ap[1];
        const float4* wp = (const float4*)(W + (size_t)(bn0 + srow) * DM + k0 + sseg * 8);
        const float4 w0 = wp[0], w1 = wp[1];
        __syncthreads();
        *(v8h*)&As[srow][sseg * 8] = cvt8(a0, a1);
        *(v8h*)&Ws[srow][sseg * 8] = cvt8(w0, w1);
        __syncthreads();
        const v8h af = *(const v8h*)&As[wave * 16 + fr][fg];
        #pragma unroll
        for (int sn = 0; sn < 4; ++sn) {
            const v8h bf = *(const v8h*)&Ws[sn * 16 + fr][fg];
            acc[sn] = __builtin_amdgcn_mfma_f32_16x16x32_f16(af, bf, acc[sn], 0, 0, 0);
        }
    }
    #pragma unroll
    for (int sn = 0; sn < 4; ++sn) {
        #pragma unroll
        for (int rg = 0; rg < 4; ++rg) {
            const int row = bm0 + wave * 16 + (lane >> 4) * 4 + rg;
            const int col = bn0 + sn * 16 + fr;
            const float val = acc[sn][rg];
            if (mat == 0)      Qh[(size_t)row * DM + col] = (_Float16)val;
            else if (mat == 1) Kh[(size_t)row * DM + col] = (_Float16)val;
            else               V[(size_t)row * DM + col] = val;
        }
    }
}

// ---------------- Stage 2: qf/kf = head-gathered Q/K @ Wa^T via MFMA --------
// M=2048 gathered rows, N=512 features, K=64 (2 MFMA k-steps).
__global__ __launch_bounds__(256) void feat_mfma(
    const _Float16* __restrict__ Qh, const _Float16* __restrict__ Kh,
    const float* __restrict__ Wqa, const float* __restrict__ Wka,
    const int* __restrict__ vl, float* __restrict__ qf, float* __restrict__ kf)
{
    const int mat = blockIdx.z;
    const int bm0 = blockIdx.y * 64, bn0 = blockIdx.x * 64;
    if (mat && (bm0 & 127) >= vl[bm0 >> 10]) return;   // masked kf rows never read
    const _Float16* Asrc = mat ? Kh : Qh;
    const float* W = mat ? Wka : Wqa;
    float* C = mat ? kf : qf;

    __shared__ _Float16 As[64][40];
    __shared__ _Float16 Ws[64][40];
    const int tid = threadIdx.x, wave = tid >> 6, lane = tid & 63;
    const int srow = tid >> 2, sseg = tid & 3;
    const int fr = lane & 15, fg = (lane >> 4) * 8;

    const int r = bm0 + srow;
    const int b = r >> 10, h = (r >> 7) & 7, l = r & 127;
    const _Float16* arow = Asrc + (size_t)(b * LQL + l) * DM + h * DH;

    v4f acc[4] = {};
    #pragma unroll
    for (int k0 = 0; k0 < DH; k0 += 32) {
        const v8h ha = *(const v8h*)(arow + k0 + sseg * 8);
        const float4* wp = (const float4*)(W + (size_t)(bn0 + srow) * DH + k0 + sseg * 8);
        const float4 w0 = wp[0], w1 = wp[1];
        __syncthreads();
        *(v8h*)&As[srow][sseg * 8] = ha;
        *(v8h*)&Ws[srow][sseg * 8] = cvt8(w0, w1);
        __syncthreads();
        const v8h af = *(const v8h*)&As[wave * 16 + fr][fg];
        #pragma unroll
        for (int sn = 0; sn < 4; ++sn) {
            const v8h bf = *(const v8h*)&Ws[sn * 16 + fr][fg];
            acc[sn] = __builtin_amdgcn_mfma_f32_16x16x32_f16(af, bf, acc[sn], 0, 0, 0);
        }
    }
    #pragma unroll
    for (int sn = 0; sn < 4; ++sn)
        #pragma unroll
        for (int rg = 0; rg < 4; ++rg) {
            const int row = bm0 + wave * 16 + (lane >> 4) * 4 + rg;
            const int col = bn0 + sn * 16 + fr;
            C[(size_t)row * DM + col] = acc[sn][rg];
        }
}

// ---------------- Stage 3: fused score + masked softmax + PV (fp32) ---------
// 256 blocks (b,h,qtile of 8), 512 thr. Thread t: k = t&127, f-quarter = t>>7.
__global__ __launch_bounds__(512, 2) void attn_kernel(
    const float* __restrict__ qf, const float* __restrict__ kf,
    const float* __restrict__ V, const float* __restrict__ wv_a,
    const int* __restrict__ vl, _Float16* __restrict__ interh)
{
    __shared__ float s_qf2[QPB][DM];
    __shared__ float s_wv2[DM];
    __shared__ float s_part[4][QPB][LKL];
    __shared__ float s_attn[QPB][LKL];

    const float C2 = 2.8853900818f;        // 2*log2(e)
    const float LOG2E = 1.4426950409f;

    const int bid = blockIdx.x;
    const int b  = bid >> 7;
    const int h  = (bid >> 4) & 7;
    const int qt = bid & 15;
    const int qbase = qt * QPB;
    const int bh = b * NHEADS + h;
    const int t = threadIdx.x;
    const int Lv = vl[b];

    {   // stage qf (pre-scaled by 2log2e) and wv (pre-scaled by -2)
        const int r = t >> 6, cc = (t & 63) * 8;
        const float4* q4 = (const float4*)(qf + ((size_t)(bh * LQL + qbase + r)) * DM + cc);
        const float4 v0 = q4[0], v1 = q4[1];
        s_qf2[r][cc+0] = v0.x * C2; s_qf2[r][cc+1] = v0.y * C2;
        s_qf2[r][cc+2] = v0.z * C2; s_qf2[r][cc+3] = v0.w * C2;
        s_qf2[r][cc+4] = v1.x * C2; s_qf2[r][cc+5] = v1.y * C2;
        s_qf2[r][cc+6] = v1.z * C2; s_qf2[r][cc+7] = v1.w * C2;
        s_wv2[t] = wv_a[t] * -2.0f;
    }
    __syncthreads();

    const int k = t & 127, fq = t >> 7;
    float acc[QPB] = {};
    if (k < Lv) {
        const float* kp = kf + ((size_t)(bh * LKL + k)) * DM + fq * 128;
        float4 kA = *(const float4*)kp;
        float4 kB = *(const float4*)(kp + 4);
        #pragma unroll 1
        for (int it = 0; it < 16; ++it) {
            float4 nA, nB;
            if (it < 15) { nA = *(const float4*)(kp + 8); nB = *(const float4*)(kp + 12); }
            else         { nA = kA; nB = kB; }
            const int f0 = fq * 128 + it * 8;
            const float4 w0 = *(const float4*)&s_wv2[f0];
            const float4 w1 = *(const float4*)&s_wv2[f0 + 4];
            #pragma unroll
            for (int q = 0; q < QPB; ++q) {
                const float4 q0 = *(const float4*)&s_qf2[q][f0];
                const float4 q1 = *(const float4*)&s_qf2[q][f0 + 4];
                float a = acc[q];
                a = fmaf(w0.x, frcp(fexp2(fmaf(kA.x, C2, q0.x)) + 1.f), a);
                a = fmaf(w0.y, frcp(fexp2(fmaf(kA.y, C2, q0.y)) + 1.f), a);
                a = fmaf(w0.z, frcp(fexp2(fmaf(kA.z, C2, q0.z)) + 1.f), a);
                a = fmaf(w0.w, frcp(fexp2(fmaf(kA.w, C2, q0.w)) + 1.f), a);
                a = fmaf(w1.x, frcp(fexp2(fmaf(kB.x, C2, q1.x)) + 1.f), a);
                a = fmaf(w1.y, frcp(fexp2(fmaf(kB.y, C2, q1.y)) + 1.f), a);
                a = fmaf(w1.z, frcp(fexp2(fmaf(kB.z, C2, q1.z)) + 1.f), a);
                a = fmaf(w1.w, frcp(fexp2(fmaf(kB.w, C2, q1.w)) + 1.f), a);
                acc[q] = a;
            }
            kA = nA; kB = nB; kp += 8;
        }
    }
    #pragma unroll
    for (int q = 0; q < QPB; ++q) s_part[fq][q][k] = acc[q];
    __syncthreads();

    {   // masked softmax: wave w = q-row w; lane covers k=lane, k=lane+64
        const int q = t >> 6, lane = t & 63;
        float v0 = -3.0e38f, v1 = -3.0e38f;
        if (lane < Lv)
            v0 = s_part[0][q][lane] + s_part[1][q][lane]
               + s_part[2][q][lane] + s_part[3][q][lane];
        if (lane + 64 < Lv)
            v1 = s_part[0][q][lane+64] + s_part[1][q][lane+64]
               + s_part[2][q][lane+64] + s_part[3][q][lane+64];
        float m = fmaxf(v0, v1);
        #pragma unroll
        for (int off = 32; off; off >>= 1) m = fmaxf(m, __shfl_xor(m, off, 64));
        const float e0 = fexp2((v0 - m) * LOG2E);
        const float e1 = fexp2((v1 - m) * LOG2E);
        float s = e0 + e1;
        #pragma unroll
        for (int off = 32; off; off >>= 1) s += __shfl_xor(s, off, 64);
        const float inv = frcp(s);
        s_attn[q][lane]      = e0 * inv;
        s_attn[q][lane + 64] = e1 * inv;
    }
    __syncthreads();

    {   // PV: thread (q = t>>6, d = t&63); only k < Lv contribute; fp16 store
        const int q = t >> 6, d = t & 63;
        const float* vb = V + ((size_t)(b * LKL)) * DM + h * DH + d;
        float a0 = 0.f, a1 = 0.f, a2 = 0.f, a3 = 0.f;
        int kk = 0;
        for (; kk + 4 <= Lv; kk += 4) {
            a0 += s_attn[q][kk+0] * vb[(size_t)(kk+0) * DM];
            a1 += s_attn[q][kk+1] * vb[(size_t)(kk+1) * DM];
            a2 += s_attn[q][kk+2] * vb[(size_t)(kk+2) * DM];
            a3 += s_attn[q][kk+3] * vb[(size_t)(kk+3) * DM];
        }
        for (; kk < Lv; ++kk) a0 += s_attn[q][kk] * vb[(size_t)kk * DM];
        interh[((size_t)(b * LQL + qbase + q)) * DM + h * DH + d] =
            (_Float16)((a0 + a1) + (a2 + a3));
    }
}

// ---------------- Stage 4: out = inter @ Wo^T via MFMA (fp32 out) -----------
__global__ __launch_bounds__(256) void out_mfma(
    const _Float16* __restrict__ interh, const float* __restrict__ Wo,
    float* __restrict__ out)
{
    const int bm0 = blockIdx.y * 64, bn0 = blockIdx.x * 64;
    __shared__ _Float16 As[64][40];
    __shared__ _Float16 Ws[64][40];
    const int tid = threadIdx.x, wave = tid >> 6, lane = tid & 63;
    const int srow = tid >> 2, sseg = tid & 3;
    const int fr = lane & 15, fg = (lane >> 4) * 8;

    v4f acc[4] = {};
    for (int k0 = 0; k0 < DM; k0 += 32) {
        const v8h ha = *(const v8h*)(interh + (size_t)(bm0 + srow) * DM + k0 + sseg * 8);
        const float4* wp = (const float4*)(Wo + (size_t)(bn0 + srow) * DM + k0 + sseg * 8);
        const float4 w0 = wp[0], w1 = wp[1];
        __syncthreads();
        *(v8h*)&As[srow][sseg * 8] = ha;
        *(v8h*)&Ws[srow][sseg * 8] = cvt8(w0, w1);
        __syncthreads();
        const v8h af = *(const v8h*)&As[wave * 16 + fr][fg];
        #pragma unroll
        for (int sn = 0; sn < 4; ++sn) {
            const v8h bf = *(const v8h*)&Ws[sn * 16 + fr][fg];
            acc[sn] = __builtin_amdgcn_mfma_f32_16x16x32_f16(af, bf, acc[sn], 0, 0, 0);
        }
    }
    #pragma unroll
    for (int sn = 0; sn < 4; ++sn)
        #pragma unroll
        for (int rg = 0; rg < 4; ++rg) {
            const int row = bm0 + wave * 16 + (lane >> 4) * 4 + rg;
            const int col = bn0 + sn * 16 + fr;
            out[(size_t)row * DM + col] = acc[sn][rg];
        }
}

extern "C" void kernel_launch(void* const* d_in, const int* in_sizes, int n_in,
                              void* d_out, int out_size, void* d_ws, size_t ws_size,
                              hipStream_t stream)
{
    const float* xq   = (const float*)d_in[0];
    const float* xk   = (const float*)d_in[1];
    const float* xv   = (const float*)d_in[2];
    const int*   vl   = (const int*)d_in[3];
    const float* Wq   = (const float*)d_in[4];
    const float* Wk   = (const float*)d_in[5];
    const float* Wv   = (const float*)d_in[6];
    const float* Wo   = (const float*)d_in[7];
    const float* Wqa  = (const float*)d_in[8];
    const float* Wka  = (const float*)d_in[9];
    const float* wv_a = (const float*)d_in[10];
    float* out = (float*)d_out;

    // ws carve (bytes): Qh 256K | Kh 256K | V 512K | qf 4M | kf 4M | interh 256K
    char* base = (char*)d_ws;
    _Float16* Qh     = (_Float16*)(base);
    _Float16* Kh     = (_Float16*)(base + 262144);
    float*    V      = (float*)   (base + 524288);
    float*    qf     = (float*)   (base + 1048576);
    float*    kf     = (float*)   (base + 5242880);
    _Float16* interh = (_Float16*)(base + 9437184);

    qkv_mfma<<<dim3(8, 4, 3), dim3(256), 0, stream>>>(
        xq, xk, xv, Wq, Wk, Wv, vl, Qh, Kh, V);
    feat_mfma<<<dim3(8, 32, 2), dim3(256), 0, stream>>>(
        Qh, Kh, Wqa, Wka, vl, qf, kf);
    attn_kernel<<<dim3(256), dim3(512), 0, stream>>>(
        qf, kf, V, wv_a, vl, interh);
    out_mfma<<<dim3(8, 4), dim3(256), 0, stream>>>(interh, Wo, out);
}